// Round 6
// baseline (209.391 us; speedup 1.0000x reference)
//
#include <hip/hip_runtime.h>

#define NCH 30                 // channels per cell (120 B)
#define W   64                 // cells per wave-chunk
#define TPB 256                // 4 waves per block
#define NV  (W * NCH / 4)      // 480 float4 per array per chunk
#define NBLK 512               // grid: 2048 waves, ~6 chunks each

typedef __attribute__((address_space(1))) const void gas_t;
typedef __attribute__((address_space(3))) void las_t;

__device__ __forceinline__ float iou_f(float x1, float y1, float w1, float h1,
                                       float x2, float y2, float w2, float h2) {
    float l1 = x1 - 0.5f * w1, r1 = x1 + 0.5f * w1;
    float t1 = y1 - 0.5f * h1, b1 = y1 + 0.5f * h1;
    float l2 = x2 - 0.5f * w2, r2 = x2 + 0.5f * w2;
    float t2 = y2 - 0.5f * h2, b2 = y2 + 0.5f * h2;
    float in_h = fminf(b1, b2) - fmaxf(t1, t2);
    float in_w = fminf(r1, r2) - fmaxf(l1, l2);
    float inter = (in_h < 0.f || in_w < 0.f) ? 0.f : in_h * in_w;
    float a1 = (b1 - t1) * (r1 - l1);
    float a2 = (b2 - t2) * (r2 - l2);
    return inter / (a1 + a2 - inter);
}

// Wave-autonomous streaming: each wave DMA-stages 64-cell chunks into its own
// private LDS region (global_load_lds, 16 B/lane, 1 KB/instr) and consumes them
// with NO block barrier in the hot loop -> 16 DMA instrs (15.4 KB) in flight
// per wave at all times.
__global__ __launch_bounds__(TPB) void yolo_partial(const float* __restrict__ pred,
                                                    const float* __restrict__ lab,
                                                    float* __restrict__ partial,
                                                    int n_chunks, int total_waves) {
    __shared__ float4 sbuf[4][2][NV];   // 61,440 B: [wave][pred/lab][float4]
    __shared__ float red[5][4];

    const int tid  = threadIdx.x;
    const int wave = tid >> 6;
    const int lane = tid & 63;
    const int wid  = blockIdx.x * 4 + wave;

    float4* sp = sbuf[wave][0];
    float4* sl = sbuf[wave][1];

    float v0 = 0.f, v1 = 0.f, v2 = 0.f, v3 = 0.f, v4 = 0.f;

    for (int ch = wid; ch < n_chunks; ch += total_waves) {
        const float4* gp = (const float4*)pred + (size_t)ch * NV;
        const float4* gl = (const float4*)lab  + (size_t)ch * NV;

        // ---- 16 async DMA issues, all outstanding simultaneously ----
#pragma unroll
        for (int k = 0; k < 7; ++k) {
            __builtin_amdgcn_global_load_lds((gas_t*)(gp + 64 * k + lane),
                                             (las_t*)(sp + 64 * k), 16, 0, 0);
            __builtin_amdgcn_global_load_lds((gas_t*)(gl + 64 * k + lane),
                                             (las_t*)(sl + 64 * k), 16, 0, 0);
        }
        if (lane < 32) {   // remaining 32 float4 of each array
            __builtin_amdgcn_global_load_lds((gas_t*)(gp + 448 + lane),
                                             (las_t*)(sp + 448), 16, 0, 0);
            __builtin_amdgcn_global_load_lds((gas_t*)(gl + 448 + lane),
                                             (las_t*)(sl + 448), 16, 0, 0);
        }
        asm volatile("s_waitcnt vmcnt(0)" ::: "memory");   // wave-local drain only

        // ---- branchless per-cell compute (cell = ch*64 + lane) ----
        const float* cp = (const float*)sp + lane * NCH;
        const float* cl = (const float*)sl + lane * NCH;
        const float mask = cl[0];
        const float gx = cl[1], gy = cl[2], gw = cl[3], gh = cl[4];

        const float i1 = iou_f(cp[1], cp[2], cp[3], cp[4], gx, gy, gw, gh);
        const float i2 = iou_f(cp[6], cp[7], cp[8], cp[9], gx, gy, gw, gh);
        const bool best = (i1 >= i2);
        const float sx = best ? cp[1] : cp[6];
        const float sy = best ? cp[2] : cp[7];
        const float sw = best ? cp[3] : cp[8];
        const float sh = best ? cp[4] : cp[9];
        const float imax = best ? i1 : i2;
        const float imin = best ? i2 : i1;

        const float center = 5.f * ((sx - gx) * (sx - gx) + (sy - gy) * (sy - gy));
        const float dw = sqrtf(sw) - sqrtf(gw);
        const float dh = sqrtf(sh) - sqrtf(gh);
        const float wh = 5.f * (dw * dw + dh * dh);

        float cls = 0.f;
#pragma unroll
        for (int c = 10; c < 30; ++c) {
            const float d = cp[c] - cl[c];
            cls += d * d;
        }

        v0 += center * mask;
        v1 += wh * mask;
        v2 += imax * mask;
        v3 += imin * mask;
        v4 += cls * mask;
    }

    // ---- Wave (64-lane) shuffle reduction ----
#pragma unroll
    for (int off = 32; off > 0; off >>= 1) {
        v0 += __shfl_down(v0, off);
        v1 += __shfl_down(v1, off);
        v2 += __shfl_down(v2, off);
        v3 += __shfl_down(v3, off);
        v4 += __shfl_down(v4, off);
    }

    if (lane == 0) {
        red[0][wave] = v0;
        red[1][wave] = v1;
        red[2][wave] = v2;
        red[3][wave] = v3;
        red[4][wave] = v4;
    }
    __syncthreads();           // only barrier in the kernel

    if (tid < 5) {
        float s = 0.f;
#pragma unroll
        for (int w = 0; w < 4; ++w) s += red[tid][w];
        partial[(size_t)blockIdx.x * 5 + tid] = s;
    }
}

// Reduce NBLK x 5 partials -> out[0..4]. One block.
__global__ __launch_bounds__(256) void final_reduce(const float* __restrict__ partial,
                                                    float* __restrict__ out,
                                                    int n_blocks) {
    __shared__ float red[5][4];
    const int tid = threadIdx.x;
    float v0 = 0.f, v1 = 0.f, v2 = 0.f, v3 = 0.f, v4 = 0.f;
    for (int b = tid; b < n_blocks; b += 256) {
        const float* q = partial + (size_t)b * 5;
        v0 += q[0]; v1 += q[1]; v2 += q[2]; v3 += q[3]; v4 += q[4];
    }
#pragma unroll
    for (int off = 32; off > 0; off >>= 1) {
        v0 += __shfl_down(v0, off);
        v1 += __shfl_down(v1, off);
        v2 += __shfl_down(v2, off);
        v3 += __shfl_down(v3, off);
        v4 += __shfl_down(v4, off);
    }
    const int wave = tid >> 6;
    const int lane = tid & 63;
    if (lane == 0) {
        red[0][wave] = v0;
        red[1][wave] = v1;
        red[2][wave] = v2;
        red[3][wave] = v3;
        red[4][wave] = v4;
    }
    __syncthreads();
    if (tid < 5) {
        float s = 0.f;
#pragma unroll
        for (int w = 0; w < 4; ++w) s += red[tid][w];
        out[tid] = s;
    }
}

extern "C" void kernel_launch(void* const* d_in, const int* in_sizes, int n_in,
                              void* d_out, int out_size, void* d_ws, size_t ws_size,
                              hipStream_t stream) {
    const float* pred = (const float*)d_in[0];
    const float* lab  = (const float*)d_in[1];
    float* out = (float*)d_out;
    float* partial = (float*)d_ws;                 // NBLK*5*4 = 10,240 B

    const int n_cells  = in_sizes[0] / NCH;        // 802816 = 64 * 12544
    const int n_chunks = n_cells / W;              // 12544
    const int total_waves = NBLK * (TPB / 64);     // 2048

    hipLaunchKernelGGL(yolo_partial, dim3(NBLK), dim3(TPB), 0, stream,
                       pred, lab, partial, n_chunks, total_waves);
    hipLaunchKernelGGL(final_reduce, dim3(1), dim3(256), 0, stream,
                       partial, out, NBLK);
}